// Round 6
// baseline (789.206 us; speedup 1.0000x reference)
//
#include <hip/hip_runtime.h>
#include <hip/hip_fp16.h>
#include <math.h>

#define TPB 256

typedef short  bf16x8 __attribute__((ext_vector_type(8)));
typedef float  f32x4  __attribute__((ext_vector_type(4)));

__device__ __forceinline__ float gelu_erf(float x){
  return 0.5f * x * (1.0f + erff(x * 0.70710678118654752440f));
}

__device__ __forceinline__ unsigned short f2bf(float f){
  union { float f; unsigned u; } v; v.f = f;
  unsigned r = v.u + 0x7fff + ((v.u >> 16) & 1);
  return (unsigned short)(r >> 16);
}
__device__ __forceinline__ float bf2f(unsigned short h){
  union { unsigned u; float f; } v; v.u = ((unsigned)h) << 16; return v.f;
}

// ---------------- CSR build ----------------

__global__ __launch_bounds__(TPB) void deg_kernel(const int* __restrict__ dst, int* __restrict__ deg, int E){
  int i = blockIdx.x * TPB + threadIdx.x;
  if (i < E) atomicAdd(&deg[dst[i]], 1);
}

// block-local exclusive scan of deg -> row_ptr; block sums -> bsums; also dinv
__global__ __launch_bounds__(TPB) void scan1(const int* __restrict__ deg, int* __restrict__ row_ptr,
                                             int* __restrict__ bsums, float* __restrict__ dinv, int n){
  int gid = blockIdx.x * TPB + threadIdx.x;
  int v = (gid < n) ? deg[gid] : 0;
  if (gid < n) dinv[gid] = rsqrtf((float)v + 2.0f);
  int lane = threadIdx.x & 63;
  int wid  = threadIdx.x >> 6;
  int x = v;
  #pragma unroll
  for (int off = 1; off < 64; off <<= 1){
    int y = __shfl_up(x, off);
    if (lane >= off) x += y;
  }
  __shared__ int wtot[TPB/64];
  __shared__ int woff[TPB/64];
  if (lane == 63) wtot[wid] = x;
  __syncthreads();
  if (threadIdx.x == 0){
    int s = 0;
    #pragma unroll
    for (int i = 0; i < TPB/64; ++i){ woff[i] = s; s += wtot[i]; }
    bsums[blockIdx.x] = s;
  }
  __syncthreads();
  if (gid < n) row_ptr[gid] = x - v + woff[wid];
}

// parallel single-block exclusive scan of block sums (nb <= 1024); also zeroes chunk_cnt[8]
__global__ __launch_bounds__(1024) void scan2p(int* __restrict__ bsums, int* __restrict__ chunk_cnt, int nb){
  __shared__ int tmp[1024];
  int t = threadIdx.x;
  if (t < 8) chunk_cnt[t] = 0;
  int v = (t < nb) ? bsums[t] : 0;
  int x = v;
  tmp[t] = x;
  __syncthreads();
  #pragma unroll
  for (int off = 1; off < 1024; off <<= 1){
    int y = (t >= off) ? tmp[t - off] : 0;
    __syncthreads();
    x += y;
    tmp[t] = x;
    __syncthreads();
  }
  if (t < nb) bsums[t] = x - v;   // exclusive
}

__global__ __launch_bounds__(TPB) void scan3(int* __restrict__ row_ptr, int* __restrict__ cursor,
                                             const int* __restrict__ boffs, int n, int E){
  int gid = blockIdx.x * TPB + threadIdx.x;
  if (gid < n){
    int v = row_ptr[gid] + boffs[blockIdx.x];
    row_ptr[gid] = v;
    cursor[gid] = v;
  }
  if (gid == 0) row_ptr[n] = E;
}

// True-XCD-partitioned CSR fill. Each block reads its REAL XCD id (hwreg 20 =
// HW_REG_XCC_ID, HW-verified 0..7 on MI355X) and serves the matching dst range,
// so all scattered csr stores for one 800KB csr slice are issued from ONE XCD's
// L2: lines accumulate ~16 dirty dwords and evict once. (R5: blockIdx%8 guess
// left 8-way cross-XCD line sharing -> WRITE 70MB.) Chunks are handed out
// dynamically per range; after draining its own range a block steals other
// ranges' leftovers, so correctness is dispatch-independent (G16).
__global__ __launch_bounds__(TPB) void fill_xcd(const int* __restrict__ src, const int* __restrict__ dst,
                                                int* __restrict__ cursor, int* __restrict__ csr_src,
                                                int* __restrict__ chunk_cnt,
                                                int E, int rstep, int G){
  int xcd;
  asm volatile("s_getreg_b32 %0, hwreg(20, 0, 32)" : "=s"(xcd));  // HW_REG_XCC_ID
  xcd &= 7;
  __shared__ int sm;
  for (int r = 0; r < 8; ++r){
    int g = (xcd + r) & 7;
    int lo = g * rstep;
    int hi = lo + rstep;
    for (;;){
      __syncthreads();
      if (threadIdx.x == 0) sm = atomicAdd(&chunk_cnt[g], 1);
      __syncthreads();
      int m = sm;
      if (m >= G) break;
      long b0 = (long)m * E / G, b1 = (long)(m + 1) * E / G;
      for (long i = b0 + threadIdx.x; i < b1; i += TPB){
        int d = dst[i];
        if (d >= lo && d < hi){
          int pos = atomicAdd(&cursor[d], 1);
          csr_src[pos] = src[i];
        }
      }
    }
  }
}

// ---------------- W split/transpose: fp32 -> bf16 hi/lo, transposed [col][k] ----------------

__global__ __launch_bounds__(TPB) void convW_all(const float* __restrict__ W0, const float* __restrict__ W1,
                                                 const float* __restrict__ W2, const float* __restrict__ W3,
                                                 unsigned short* __restrict__ Wh, unsigned short* __restrict__ Wl){
  int gid = blockIdx.x * TPB + threadIdx.x;
  if (gid < 3*16384){
    int which = gid >> 14, idx = gid & 16383;
    int c = idx >> 7, k = idx & 127;
    const float* W = (which == 0) ? W0 : (which == 1) ? W1 : W2;
    float f = W[k*128 + c];
    unsigned short h = f2bf(f);
    unsigned short l = f2bf(f - bf2f(h));
    Wh[gid] = h; Wl[gid] = l;
  } else if (gid < 3*16384 + 48*128){
    int idx = gid - 3*16384;
    int c = idx >> 7, k = idx & 127;
    float f = (c < 40) ? W3[k*40 + c] : 0.f;
    unsigned short h = f2bf(f);
    unsigned short l = f2bf(f - bf2f(h));
    Wh[gid] = h; Wl[gid] = l;
  }
}

// ---------------- MFMA GEMM: C[N x NC] = A[N x 128] @ W[128 x NC] (+bias) ----------------

template<int NCT, int NC, bool BIAS, typename CT>
__global__ __launch_bounds__(TPB) void gemm_mfma(const float* __restrict__ A,
                                                 const unsigned short* __restrict__ Wh,
                                                 const unsigned short* __restrict__ Wl,
                                                 const float* __restrict__ bias,
                                                 CT* __restrict__ C, int n){
  int wave = threadIdx.x >> 6;
  int lane = threadIdx.x & 63;
  int q    = lane >> 4;
  int m16  = lane & 15;
  int r0   = blockIdx.x * 128 + wave * 32;

  f32x4 acc[2][NCT];
  #pragma unroll
  for (int rt = 0; rt < 2; ++rt)
    #pragma unroll
    for (int ct = 0; ct < NCT; ++ct)
      acc[rt][ct] = (f32x4){0.f, 0.f, 0.f, 0.f};

  for (int k0 = 0; k0 < 128; k0 += 32){
    bf16x8 ah[2], al[2];
    #pragma unroll
    for (int rt = 0; rt < 2; ++rt){
      int r = r0 + rt*16 + m16;
      if (r > n-1) r = n-1;
      const float* ap = A + (size_t)r*128 + k0 + q*8;
      float4 f0 = *(const float4*)(ap);
      float4 f1 = *(const float4*)(ap + 4);
      float fv[8] = {f0.x, f0.y, f0.z, f0.w, f1.x, f1.y, f1.z, f1.w};
      #pragma unroll
      for (int j = 0; j < 8; ++j){
        unsigned short h = f2bf(fv[j]);
        unsigned short l = f2bf(fv[j] - bf2f(h));
        ah[rt][j] = (short)h;
        al[rt][j] = (short)l;
      }
    }
    #pragma unroll
    for (int ct = 0; ct < NCT; ++ct){
      int c = ct*16 + m16;
      const unsigned short* ph = Wh + (size_t)c*128 + k0 + q*8;
      const unsigned short* pl = Wl + (size_t)c*128 + k0 + q*8;
      bf16x8 bh = *(const bf16x8*)ph;
      bf16x8 bl = *(const bf16x8*)pl;
      #pragma unroll
      for (int rt = 0; rt < 2; ++rt){
        acc[rt][ct] = __builtin_amdgcn_mfma_f32_16x16x32_bf16(ah[rt], bh, acc[rt][ct], 0, 0, 0);
        acc[rt][ct] = __builtin_amdgcn_mfma_f32_16x16x32_bf16(ah[rt], bl, acc[rt][ct], 0, 0, 0);
        acc[rt][ct] = __builtin_amdgcn_mfma_f32_16x16x32_bf16(al[rt], bh, acc[rt][ct], 0, 0, 0);
      }
    }
  }
  #pragma unroll
  for (int rt = 0; rt < 2; ++rt){
    #pragma unroll
    for (int ct = 0; ct < NCT; ++ct){
      int c = ct*16 + m16;
      if (c < NC){
        float bv = BIAS ? bias[c] : 0.f;
        #pragma unroll
        for (int i = 0; i < 4; ++i){
          int r = r0 + rt*16 + q*4 + i;
          if (r < n) C[(size_t)r*NC + c] = (CT)(acc[rt][ct][i] + bv);
        }
      }
    }
  }
}

// ---------------- Aggregation: 16 lanes per dst node, 8 fp16 feats (16 B) per lane ----------------

template<int MODE, bool OUTH>
__global__ __launch_bounds__(TPB) void agg_h(const __half* __restrict__ xh, const float* __restrict__ resf,
                                             const float* __restrict__ dinv, const int* __restrict__ row_ptr,
                                             const int* __restrict__ csr_src, const float* __restrict__ bias,
                                             void* __restrict__ outp, int n){
  int g = (int)((blockIdx.x * (unsigned)TPB + threadIdx.x) >> 4);
  if (g >= n) return;
  int lane = threadIdx.x & 15;
  float di = dinv[g];
  int beg = row_ptr[g], end = row_ptr[g+1];

  float accA[8], accB[8];
  #pragma unroll
  for (int i = 0; i < 8; ++i){ accA[i] = 0.f; accB[i] = 0.f; }

  for (int base = beg; base < end; base += 16){
    int m = end - base; if (m > 16) m = 16;
    int   sl = (lane < m) ? csr_src[base + lane] : 0;
    float cl = (lane < m) ? dinv[sl] * di : 0.f;
    int mm = (m + 1) & ~1;
    for (int j = 0; j < mm; j += 2){
      int   s0 = __shfl(sl, j,   16), s1 = __shfl(sl, j+1, 16);
      float c0 = __shfl(cl, j,   16), c1 = __shfl(cl, j+1, 16);
      uint4 u0 = *(const uint4*)(xh + (size_t)s0 * 128 + lane * 8);
      uint4 u1 = *(const uint4*)(xh + (size_t)s1 * 128 + lane * 8);
      const __half2* h0 = (const __half2*)&u0;
      const __half2* h1 = (const __half2*)&u1;
      #pragma unroll
      for (int i = 0; i < 4; ++i){
        float2 f0 = __half22float2(h0[i]);
        float2 f1 = __half22float2(h1[i]);
        accA[2*i]   = fmaf(c0, f0.x, accA[2*i]);
        accA[2*i+1] = fmaf(c0, f0.y, accA[2*i+1]);
        accB[2*i]   = fmaf(c1, f1.x, accB[2*i]);
        accB[2*i+1] = fmaf(c1, f1.y, accB[2*i+1]);
      }
    }
  }
  // self loop
  {
    float sc = 2.0f * di * di;
    uint4 u = *(const uint4*)(xh + (size_t)g * 128 + lane * 8);
    const __half2* h = (const __half2*)&u;
    #pragma unroll
    for (int i = 0; i < 4; ++i){
      float2 f = __half22float2(h[i]);
      accA[2*i]   = fmaf(sc, f.x, accA[2*i]);
      accA[2*i+1] = fmaf(sc, f.y, accA[2*i+1]);
    }
  }
  #pragma unroll
  for (int i = 0; i < 8; ++i) accA[i] += accB[i];

  if (MODE != 2){
    float4 b0 = *(const float4*)(bias + lane*8);
    float4 b1 = *(const float4*)(bias + lane*8 + 4);
    accA[0]+=b0.x; accA[1]+=b0.y; accA[2]+=b0.z; accA[3]+=b0.w;
    accA[4]+=b1.x; accA[5]+=b1.y; accA[6]+=b1.z; accA[7]+=b1.w;
  }
  if (MODE == 1){
    float4 r0 = *(const float4*)(resf + (size_t)g*128 + lane*8);
    float4 r1 = *(const float4*)(resf + (size_t)g*128 + lane*8 + 4);
    accA[0]+=r0.x; accA[1]+=r0.y; accA[2]+=r0.z; accA[3]+=r0.w;
    accA[4]+=r1.x; accA[5]+=r1.y; accA[6]+=r1.z; accA[7]+=r1.w;
  }
  if (MODE != 2){
    #pragma unroll
    for (int i = 0; i < 8; ++i) accA[i] = gelu_erf(accA[i]);
  }
  if (OUTH){
    __half hv[8];
    #pragma unroll
    for (int i = 0; i < 8; ++i) hv[i] = __float2half(accA[i]);
    *(uint4*)((__half*)outp + (size_t)g*128 + lane*8) = *(const uint4*)hv;
  } else {
    float* op = (float*)outp + (size_t)g*128 + lane*8;
    *(float4*)op       = make_float4(accA[0],accA[1],accA[2],accA[3]);
    *(float4*)(op + 4) = make_float4(accA[4],accA[5],accA[6],accA[7]);
  }
}

// ---------------- launch ----------------

extern "C" void kernel_launch(void* const* d_in, const int* in_sizes, int n_in,
                              void* d_out, int out_size, void* d_ws, size_t ws_size,
                              hipStream_t stream){
  const float* x  = (const float*)d_in[0];
  const int*   ei = (const int*)d_in[1];
  const float* W0 = (const float*)d_in[2];
  const float* b0 = (const float*)d_in[3];
  const float* W1 = (const float*)d_in[4];
  const float* b1 = (const float*)d_in[5];
  const float* W2 = (const float*)d_in[6];
  const float* b2 = (const float*)d_in[7];
  const float* W3 = (const float*)d_in[8];
  const float* b3 = (const float*)d_in[9];
  float* out = (float*)d_out;

  const int N = in_sizes[0] / 128;
  const int E = in_sizes[1] / 2;
  const int* src = ei;
  const int* dst = ei + E;

  char* ws = (char*)d_ws;
  size_t off = 0;
  auto alloc = [&](size_t bytes) -> void* {
    void* p = ws + off;
    off += (bytes + 255) & ~(size_t)255;
    return p;
  };
  __half* xw_h  = (__half*)alloc((size_t)N * 128 * 2);
  float*  gA    = (float*) alloc((size_t)N * 128 * 4);
  float*  gB    = (float*) alloc((size_t)N * 128 * 4);
  __half* gAh   = (__half*)alloc((size_t)N * 128 * 2);
  int* csr      = (int*)   alloc((size_t)E * 4);
  int* row_ptr  = (int*)   alloc((size_t)(N + 1) * 4);
  int* deg      = (int*)   alloc((size_t)N * 4);
  int* cursor   = (int*)   alloc((size_t)N * 4);
  float* dnv    = (float*) alloc((size_t)N * 4);
  int nb = (N + TPB - 1) / TPB;
  int* bsums    = (int*)   alloc((size_t)nb * 4);
  int* chunk_cnt= (int*)   alloc((size_t)8 * 4);
  const int WTOT = 3*16384 + 48*128;
  unsigned short* Wh = (unsigned short*)alloc((size_t)WTOT * 2);
  unsigned short* Wl = (unsigned short*)alloc((size_t)WTOT * 2);
  (void)ws_size; (void)n_in; (void)out_size;

  hipMemsetAsync(deg, 0, (size_t)N * 4, stream);

  int ebl = (E + TPB - 1) / TPB;
  convW_all<<<(WTOT + TPB - 1)/TPB, TPB, 0, stream>>>(W0, W1, W2, W3, Wh, Wl);
  deg_kernel<<<ebl, TPB, 0, stream>>>(dst, deg, E);
  scan1<<<nb, TPB, 0, stream>>>(deg, row_ptr, bsums, dnv, N);
  scan2p<<<1, 1024, 0, stream>>>(bsums, chunk_cnt, nb);
  scan3<<<nb, TPB, 0, stream>>>(row_ptr, cursor, bsums, N, E);
  // XCD-pinned fill: dynamic chunks per range, work-stealing fallback
  {
    const int G = 128;
    int rstep = (N + 7) / 8;
    fill_xcd<<<1024, TPB, 0, stream>>>(src, dst, cursor, csr, chunk_cnt, E, rstep, G);
  }

  int gblocks = (N + 127) / 128;
  int ablocks = ((size_t)N * 16 + TPB - 1) / TPB;

  const unsigned short* W0h = Wh,          *W0l = Wl;
  const unsigned short* W1h = Wh + 16384,  *W1l = Wl + 16384;
  const unsigned short* W2h = Wh + 32768,  *W2l = Wl + 32768;
  const unsigned short* W3h = Wh + 49152,  *W3l = Wl + 49152;

  // L0: gA = gelu(conv(x))
  gemm_mfma<8,128,false,__half><<<gblocks, TPB, 0, stream>>>(x, W0h, W0l, nullptr, xw_h, N);
  agg_h<0,false><<<ablocks, TPB, 0, stream>>>(xw_h, nullptr, dnv, row_ptr, csr, b0, gA, N);
  // L1: gB = gelu(gA + conv(gA))
  gemm_mfma<8,128,false,__half><<<gblocks, TPB, 0, stream>>>(gA, W1h, W1l, nullptr, xw_h, N);
  agg_h<1,false><<<ablocks, TPB, 0, stream>>>(xw_h, gA, dnv, row_ptr, csr, b1, gB, N);
  // L2: gAh = gelu(gB + conv(gB))  (fp16 out, feeds gather-only consumer)
  gemm_mfma<8,128,false,__half><<<gblocks, TPB, 0, stream>>>(gB, W2h, W2l, nullptr, xw_h, N);
  agg_h<1,true><<<ablocks, TPB, 0, stream>>>(xw_h, gB, dnv, row_ptr, csr, b2, gAh, N);
  // L3: out = Agg(gAh) @ W3 + b3
  agg_h<2,false><<<ablocks, TPB, 0, stream>>>(gAh, nullptr, dnv, row_ptr, csr, nullptr, gA, N);
  gemm_mfma<3,40,true,float><<<gblocks, TPB, 0, stream>>>(gA, W3h, W3l, b3, out, N);
}

// Round 7
// 691.338 us; speedup vs baseline: 1.1416x; 1.1416x over previous
//
#include <hip/hip_runtime.h>
#include <hip/hip_fp16.h>
#include <math.h>

#define TPB 256

typedef short  bf16x8 __attribute__((ext_vector_type(8)));
typedef float  f32x4  __attribute__((ext_vector_type(4)));

__device__ __forceinline__ float gelu_erf(float x){
  return 0.5f * x * (1.0f + erff(x * 0.70710678118654752440f));
}

__device__ __forceinline__ unsigned short f2bf(float f){
  union { float f; unsigned u; } v; v.f = f;
  unsigned r = v.u + 0x7fff + ((v.u >> 16) & 1);
  return (unsigned short)(r >> 16);
}
__device__ __forceinline__ float bf2f(unsigned short h){
  union { unsigned u; float f; } v; v.u = ((unsigned)h) << 16; return v.f;
}

// ---------------- CSR build ----------------

__global__ __launch_bounds__(TPB) void deg_kernel(const int* __restrict__ dst, int* __restrict__ deg, int E){
  int i = blockIdx.x * TPB + threadIdx.x;
  if (i < E) atomicAdd(&deg[__builtin_nontemporal_load(&dst[i])], 1);
}

// block-local exclusive scan of deg -> row_ptr; block sums -> bsums; also dinv
__global__ __launch_bounds__(TPB) void scan1(const int* __restrict__ deg, int* __restrict__ row_ptr,
                                             int* __restrict__ bsums, float* __restrict__ dinv, int n){
  int gid = blockIdx.x * TPB + threadIdx.x;
  int v = (gid < n) ? deg[gid] : 0;
  if (gid < n) dinv[gid] = rsqrtf((float)v + 2.0f);
  int lane = threadIdx.x & 63;
  int wid  = threadIdx.x >> 6;
  int x = v;
  #pragma unroll
  for (int off = 1; off < 64; off <<= 1){
    int y = __shfl_up(x, off);
    if (lane >= off) x += y;
  }
  __shared__ int wtot[TPB/64];
  __shared__ int woff[TPB/64];
  if (lane == 63) wtot[wid] = x;
  __syncthreads();
  if (threadIdx.x == 0){
    int s = 0;
    #pragma unroll
    for (int i = 0; i < TPB/64; ++i){ woff[i] = s; s += wtot[i]; }
    bsums[blockIdx.x] = s;
  }
  __syncthreads();
  if (gid < n) row_ptr[gid] = x - v + woff[wid];
}

// parallel single-block exclusive scan of block sums (nb <= 1024)
__global__ __launch_bounds__(1024) void scan2p(int* __restrict__ bsums, int nb){
  __shared__ int tmp[1024];
  int t = threadIdx.x;
  int v = (t < nb) ? bsums[t] : 0;
  int x = v;
  tmp[t] = x;
  __syncthreads();
  #pragma unroll
  for (int off = 1; off < 1024; off <<= 1){
    int y = (t >= off) ? tmp[t - off] : 0;
    __syncthreads();
    x += y;
    tmp[t] = x;
    __syncthreads();
  }
  if (t < nb) bsums[t] = x - v;   // exclusive
}

__global__ __launch_bounds__(TPB) void scan3(int* __restrict__ row_ptr, int* __restrict__ cursor,
                                             const int* __restrict__ boffs, int n, int E){
  int gid = blockIdx.x * TPB + threadIdx.x;
  if (gid < n){
    int v = row_ptr[gid] + boffs[blockIdx.x];
    row_ptr[gid] = v;
    cursor[gid] = v;
  }
  if (gid == 0) row_ptr[n] = E;
}

// Range-partitioned CSR fill (R5 structure). blockIdx&7 selects dst range.
// NEW (R7): edge-list reads are NON-TEMPORAL so the 6.4MB/sweep read stream
// does not allocate in L2 and evict the dirty csr lines before they fill
// (R5/R6: WRITE 70MB = ~1.1M partial-line evictions; HBM3E has no byte-mask
// writes, so partial evictions cost controller RMW at ~1 TB/s effective).
__global__ __launch_bounds__(TPB) void fill_part(const int* __restrict__ src, const int* __restrict__ dst,
                                                 int* __restrict__ cursor, int* __restrict__ csr_src,
                                                 int E, int rstep, int G){
  int g = blockIdx.x & 7;
  int m = blockIdx.x >> 3;
  int lo = g * rstep, hi = lo + rstep;
  long b0 = (long)m * E / G, b1 = (long)(m + 1) * E / G;
  for (long i = b0 + threadIdx.x; i < b1; i += TPB){
    int d = __builtin_nontemporal_load(&dst[i]);
    if (d >= lo && d < hi){
      int s = __builtin_nontemporal_load(&src[i]);
      int pos = atomicAdd(&cursor[d], 1);
      csr_src[pos] = s;
    }
  }
}

// ---------------- W split/transpose: fp32 -> bf16 hi/lo, transposed [col][k] ----------------

__global__ __launch_bounds__(TPB) void convW_all(const float* __restrict__ W0, const float* __restrict__ W1,
                                                 const float* __restrict__ W2, const float* __restrict__ W3,
                                                 unsigned short* __restrict__ Wh, unsigned short* __restrict__ Wl){
  int gid = blockIdx.x * TPB + threadIdx.x;
  if (gid < 3*16384){
    int which = gid >> 14, idx = gid & 16383;
    int c = idx >> 7, k = idx & 127;
    const float* W = (which == 0) ? W0 : (which == 1) ? W1 : W2;
    float f = W[k*128 + c];
    unsigned short h = f2bf(f);
    unsigned short l = f2bf(f - bf2f(h));
    Wh[gid] = h; Wl[gid] = l;
  } else if (gid < 3*16384 + 48*128){
    int idx = gid - 3*16384;
    int c = idx >> 7, k = idx & 127;
    float f = (c < 40) ? W3[k*40 + c] : 0.f;
    unsigned short h = f2bf(f);
    unsigned short l = f2bf(f - bf2f(h));
    Wh[gid] = h; Wl[gid] = l;
  }
}

// ---------------- MFMA GEMM: C[N x NC] = A[N x 128] @ W[128 x NC] (+bias) ----------------

template<int NCT, int NC, bool BIAS, typename CT>
__global__ __launch_bounds__(TPB) void gemm_mfma(const float* __restrict__ A,
                                                 const unsigned short* __restrict__ Wh,
                                                 const unsigned short* __restrict__ Wl,
                                                 const float* __restrict__ bias,
                                                 CT* __restrict__ C, int n){
  int wave = threadIdx.x >> 6;
  int lane = threadIdx.x & 63;
  int q    = lane >> 4;
  int m16  = lane & 15;
  int r0   = blockIdx.x * 128 + wave * 32;

  f32x4 acc[2][NCT];
  #pragma unroll
  for (int rt = 0; rt < 2; ++rt)
    #pragma unroll
    for (int ct = 0; ct < NCT; ++ct)
      acc[rt][ct] = (f32x4){0.f, 0.f, 0.f, 0.f};

  for (int k0 = 0; k0 < 128; k0 += 32){
    bf16x8 ah[2], al[2];
    #pragma unroll
    for (int rt = 0; rt < 2; ++rt){
      int r = r0 + rt*16 + m16;
      if (r > n-1) r = n-1;
      const float* ap = A + (size_t)r*128 + k0 + q*8;
      float4 f0 = *(const float4*)(ap);
      float4 f1 = *(const float4*)(ap + 4);
      float fv[8] = {f0.x, f0.y, f0.z, f0.w, f1.x, f1.y, f1.z, f1.w};
      #pragma unroll
      for (int j = 0; j < 8; ++j){
        unsigned short h = f2bf(fv[j]);
        unsigned short l = f2bf(fv[j] - bf2f(h));
        ah[rt][j] = (short)h;
        al[rt][j] = (short)l;
      }
    }
    #pragma unroll
    for (int ct = 0; ct < NCT; ++ct){
      int c = ct*16 + m16;
      const unsigned short* ph = Wh + (size_t)c*128 + k0 + q*8;
      const unsigned short* pl = Wl + (size_t)c*128 + k0 + q*8;
      bf16x8 bh = *(const bf16x8*)ph;
      bf16x8 bl = *(const bf16x8*)pl;
      #pragma unroll
      for (int rt = 0; rt < 2; ++rt){
        acc[rt][ct] = __builtin_amdgcn_mfma_f32_16x16x32_bf16(ah[rt], bh, acc[rt][ct], 0, 0, 0);
        acc[rt][ct] = __builtin_amdgcn_mfma_f32_16x16x32_bf16(ah[rt], bl, acc[rt][ct], 0, 0, 0);
        acc[rt][ct] = __builtin_amdgcn_mfma_f32_16x16x32_bf16(al[rt], bh, acc[rt][ct], 0, 0, 0);
      }
    }
  }
  #pragma unroll
  for (int rt = 0; rt < 2; ++rt){
    #pragma unroll
    for (int ct = 0; ct < NCT; ++ct){
      int c = ct*16 + m16;
      if (c < NC){
        float bv = BIAS ? bias[c] : 0.f;
        #pragma unroll
        for (int i = 0; i < 4; ++i){
          int r = r0 + rt*16 + q*4 + i;
          if (r < n) C[(size_t)r*NC + c] = (CT)(acc[rt][ct][i] + bv);
        }
      }
    }
  }
}

// ---------------- Aggregation: 16 lanes per dst node, 8 fp16 feats (16 B) per lane ----------------

template<int MODE, bool OUTH>
__global__ __launch_bounds__(TPB) void agg_h(const __half* __restrict__ xh, const float* __restrict__ resf,
                                             const float* __restrict__ dinv, const int* __restrict__ row_ptr,
                                             const int* __restrict__ csr_src, const float* __restrict__ bias,
                                             void* __restrict__ outp, int n){
  int g = (int)((blockIdx.x * (unsigned)TPB + threadIdx.x) >> 4);
  if (g >= n) return;
  int lane = threadIdx.x & 15;
  float di = dinv[g];
  int beg = row_ptr[g], end = row_ptr[g+1];

  float accA[8], accB[8];
  #pragma unroll
  for (int i = 0; i < 8; ++i){ accA[i] = 0.f; accB[i] = 0.f; }

  for (int base = beg; base < end; base += 16){
    int m = end - base; if (m > 16) m = 16;
    int   sl = (lane < m) ? csr_src[base + lane] : 0;
    float cl = (lane < m) ? dinv[sl] * di : 0.f;
    int mm = (m + 1) & ~1;
    for (int j = 0; j < mm; j += 2){
      int   s0 = __shfl(sl, j,   16), s1 = __shfl(sl, j+1, 16);
      float c0 = __shfl(cl, j,   16), c1 = __shfl(cl, j+1, 16);
      uint4 u0 = *(const uint4*)(xh + (size_t)s0 * 128 + lane * 8);
      uint4 u1 = *(const uint4*)(xh + (size_t)s1 * 128 + lane * 8);
      const __half2* h0 = (const __half2*)&u0;
      const __half2* h1 = (const __half2*)&u1;
      #pragma unroll
      for (int i = 0; i < 4; ++i){
        float2 f0 = __half22float2(h0[i]);
        float2 f1 = __half22float2(h1[i]);
        accA[2*i]   = fmaf(c0, f0.x, accA[2*i]);
        accA[2*i+1] = fmaf(c0, f0.y, accA[2*i+1]);
        accB[2*i]   = fmaf(c1, f1.x, accB[2*i]);
        accB[2*i+1] = fmaf(c1, f1.y, accB[2*i+1]);
      }
    }
  }
  // self loop
  {
    float sc = 2.0f * di * di;
    uint4 u = *(const uint4*)(xh + (size_t)g * 128 + lane * 8);
    const __half2* h = (const __half2*)&u;
    #pragma unroll
    for (int i = 0; i < 4; ++i){
      float2 f = __half22float2(h[i]);
      accA[2*i]   = fmaf(sc, f.x, accA[2*i]);
      accA[2*i+1] = fmaf(sc, f.y, accA[2*i+1]);
    }
  }
  #pragma unroll
  for (int i = 0; i < 8; ++i) accA[i] += accB[i];

  if (MODE != 2){
    float4 b0 = *(const float4*)(bias + lane*8);
    float4 b1 = *(const float4*)(bias + lane*8 + 4);
    accA[0]+=b0.x; accA[1]+=b0.y; accA[2]+=b0.z; accA[3]+=b0.w;
    accA[4]+=b1.x; accA[5]+=b1.y; accA[6]+=b1.z; accA[7]+=b1.w;
  }
  if (MODE == 1){
    float4 r0 = *(const float4*)(resf + (size_t)g*128 + lane*8);
    float4 r1 = *(const float4*)(resf + (size_t)g*128 + lane*8 + 4);
    accA[0]+=r0.x; accA[1]+=r0.y; accA[2]+=r0.z; accA[3]+=r0.w;
    accA[4]+=r1.x; accA[5]+=r1.y; accA[6]+=r1.z; accA[7]+=r1.w;
  }
  if (MODE != 2){
    #pragma unroll
    for (int i = 0; i < 8; ++i) accA[i] = gelu_erf(accA[i]);
  }
  if (OUTH){
    __half hv[8];
    #pragma unroll
    for (int i = 0; i < 8; ++i) hv[i] = __float2half(accA[i]);
    *(uint4*)((__half*)outp + (size_t)g*128 + lane*8) = *(const uint4*)hv;
  } else {
    float* op = (float*)outp + (size_t)g*128 + lane*8;
    *(float4*)op       = make_float4(accA[0],accA[1],accA[2],accA[3]);
    *(float4*)(op + 4) = make_float4(accA[4],accA[5],accA[6],accA[7]);
  }
}

// ---------------- launch ----------------

extern "C" void kernel_launch(void* const* d_in, const int* in_sizes, int n_in,
                              void* d_out, int out_size, void* d_ws, size_t ws_size,
                              hipStream_t stream){
  const float* x  = (const float*)d_in[0];
  const int*   ei = (const int*)d_in[1];
  const float* W0 = (const float*)d_in[2];
  const float* b0 = (const float*)d_in[3];
  const float* W1 = (const float*)d_in[4];
  const float* b1 = (const float*)d_in[5];
  const float* W2 = (const float*)d_in[6];
  const float* b2 = (const float*)d_in[7];
  const float* W3 = (const float*)d_in[8];
  const float* b3 = (const float*)d_in[9];
  float* out = (float*)d_out;

  const int N = in_sizes[0] / 128;
  const int E = in_sizes[1] / 2;
  const int* src = ei;
  const int* dst = ei + E;

  char* ws = (char*)d_ws;
  size_t off = 0;
  auto alloc = [&](size_t bytes) -> void* {
    void* p = ws + off;
    off += (bytes + 255) & ~(size_t)255;
    return p;
  };
  __half* xw_h  = (__half*)alloc((size_t)N * 128 * 2);
  float*  gA    = (float*) alloc((size_t)N * 128 * 4);
  float*  gB    = (float*) alloc((size_t)N * 128 * 4);
  __half* gAh   = (__half*)alloc((size_t)N * 128 * 2);
  int* csr      = (int*)   alloc((size_t)E * 4);
  int* row_ptr  = (int*)   alloc((size_t)(N + 1) * 4);
  int* deg      = (int*)   alloc((size_t)N * 4);
  int* cursor   = (int*)   alloc((size_t)N * 4);
  float* dnv    = (float*) alloc((size_t)N * 4);
  int nb = (N + TPB - 1) / TPB;
  int* bsums    = (int*)   alloc((size_t)nb * 4);
  const int WTOT = 3*16384 + 48*128;
  unsigned short* Wh = (unsigned short*)alloc((size_t)WTOT * 2);
  unsigned short* Wl = (unsigned short*)alloc((size_t)WTOT * 2);
  (void)ws_size; (void)n_in; (void)out_size;

  hipMemsetAsync(deg, 0, (size_t)N * 4, stream);

  int ebl = (E + TPB - 1) / TPB;
  convW_all<<<(WTOT + TPB - 1)/TPB, TPB, 0, stream>>>(W0, W1, W2, W3, Wh, Wl);
  deg_kernel<<<ebl, TPB, 0, stream>>>(dst, deg, E);
  scan1<<<nb, TPB, 0, stream>>>(deg, row_ptr, bsums, dnv, N);
  scan2p<<<1, 1024, 0, stream>>>(bsums, nb);
  scan3<<<nb, TPB, 0, stream>>>(row_ptr, cursor, bsums, N, E);
  // Range-partitioned fill with non-temporal edge reads
  {
    const int G = 128;
    int rstep = (N + 7) / 8;
    fill_part<<<8 * G, TPB, 0, stream>>>(src, dst, cursor, csr, E, rstep, G);
  }

  int gblocks = (N + 127) / 128;
  int ablocks = ((size_t)N * 16 + TPB - 1) / TPB;

  const unsigned short* W0h = Wh,          *W0l = Wl;
  const unsigned short* W1h = Wh + 16384,  *W1l = Wl + 16384;
  const unsigned short* W2h = Wh + 32768,  *W2l = Wl + 32768;
  const unsigned short* W3h = Wh + 49152,  *W3l = Wl + 49152;

  // L0: gA = gelu(conv(x))
  gemm_mfma<8,128,false,__half><<<gblocks, TPB, 0, stream>>>(x, W0h, W0l, nullptr, xw_h, N);
  agg_h<0,false><<<ablocks, TPB, 0, stream>>>(xw_h, nullptr, dnv, row_ptr, csr, b0, gA, N);
  // L1: gB = gelu(gA + conv(gA))
  gemm_mfma<8,128,false,__half><<<gblocks, TPB, 0, stream>>>(gA, W1h, W1l, nullptr, xw_h, N);
  agg_h<1,false><<<ablocks, TPB, 0, stream>>>(xw_h, gA, dnv, row_ptr, csr, b1, gB, N);
  // L2: gAh = gelu(gB + conv(gB))  (fp16 out, feeds gather-only consumer)
  gemm_mfma<8,128,false,__half><<<gblocks, TPB, 0, stream>>>(gB, W2h, W2l, nullptr, xw_h, N);
  agg_h<1,true><<<ablocks, TPB, 0, stream>>>(xw_h, gB, dnv, row_ptr, csr, b2, gAh, N);
  // L3: out = Agg(gAh) @ W3 + b3
  agg_h<2,false><<<ablocks, TPB, 0, stream>>>(gAh, nullptr, dnv, row_ptr, csr, nullptr, gA, N);
  gemm_mfma<3,40,true,float><<<gblocks, TPB, 0, stream>>>(gA, W3h, W3l, b3, out, N);
}

// Round 8
// 592.721 us; speedup vs baseline: 1.3315x; 1.1664x over previous
//
#include <hip/hip_runtime.h>
#include <hip/hip_fp16.h>
#include <math.h>

#define TPB 256
#define BKT 256     // dst buckets
#define CHK 256     // edge chunks
#define CAP 12288   // LDS edge cache per bucket (avg 6250 for E=1.6M)

typedef short  bf16x8 __attribute__((ext_vector_type(8)));
typedef float  f32x4  __attribute__((ext_vector_type(4)));

__device__ __forceinline__ float gelu_erf(float x){
  return 0.5f * x * (1.0f + erff(x * 0.70710678118654752440f));
}

__device__ __forceinline__ unsigned short f2bf(float f){
  union { float f; unsigned u; } v; v.f = f;
  unsigned r = v.u + 0x7fff + ((v.u >> 16) & 1);
  return (unsigned short)(r >> 16);
}
__device__ __forceinline__ float bf2f(unsigned short h){
  union { unsigned u; float f; } v; v.u = ((unsigned)h) << 16; return v.f;
}

// ---------------- CSR build: bucketed counting sort ----------------
// R3-R7 lesson: atomic-scatter fill has ~1 partial-line eviction per edge
// (each csr line receives its 16 dwords from ~16 different blocks at different
// times; WRITE_SIZE stayed 66-108MB across nt-store/XCD-pin/nt-load attempts).
// Counting sort gives every (chunk,bucket) a contiguous run -> locality by
// construction, and bucket-local CSR placement is single-block -> lines fill.

// pass 1: hist[bucket][chunk] = count
__global__ __launch_bounds__(TPB) void hist_kernel(const int* __restrict__ dst,
                                                   int* __restrict__ hist, int E, int nper){
  __shared__ int h[BKT];
  for (int i = threadIdx.x; i < BKT; i += TPB) h[i] = 0;
  __syncthreads();
  int m = blockIdx.x;
  long b0 = (long)m * E / CHK, b1 = (long)(m + 1) * E / CHK;
  for (long i = b0 + threadIdx.x; i < b1; i += TPB){
    int d = __builtin_nontemporal_load(&dst[i]);
    atomicAdd(&h[d / nper], 1);
  }
  __syncthreads();
  for (int i = threadIdx.x; i < BKT; i += TPB) hist[i * CHK + m] = h[i];
}

// pass 2a: per-bucket exclusive scan over chunks; bucket totals -> btot
__global__ __launch_bounds__(CHK) void scanA(int* __restrict__ hist, int* __restrict__ btot){
  __shared__ int tmp[CHK];
  int b = blockIdx.x, t = threadIdx.x;
  int v = hist[b * CHK + t];
  int x = v;
  tmp[t] = x;
  __syncthreads();
  #pragma unroll
  for (int off = 1; off < CHK; off <<= 1){
    int y = (t >= off) ? tmp[t - off] : 0;
    __syncthreads();
    x += y;
    tmp[t] = x;
    __syncthreads();
  }
  hist[b * CHK + t] = x - v;
  if (t == CHK - 1) btot[b] = x;
}

// pass 2b: exclusive scan of bucket totals -> bbase[0..BKT], bbase[BKT]=E
__global__ __launch_bounds__(BKT) void scanB(const int* __restrict__ btot, int* __restrict__ bbase, int E){
  __shared__ int tmp[BKT];
  int t = threadIdx.x;
  int v = btot[t];
  int x = v;
  tmp[t] = x;
  __syncthreads();
  #pragma unroll
  for (int off = 1; off < BKT; off <<= 1){
    int y = (t >= off) ? tmp[t - off] : 0;
    __syncthreads();
    x += y;
    tmp[t] = x;
    __syncthreads();
  }
  bbase[t] = x - v;
  if (t == 0) bbase[BKT] = E;
}

// pass 3: scatter edges into bucket-contiguous runs, packed (dst_local<<17)|src
__global__ __launch_bounds__(TPB) void bucket_scatter(const int* __restrict__ src, const int* __restrict__ dst,
                                                      const int* __restrict__ hist, const int* __restrict__ bbase,
                                                      int* __restrict__ bucketed, int E, int nper){
  __shared__ int offs[BKT];
  int m = blockIdx.x;
  for (int i = threadIdx.x; i < BKT; i += TPB) offs[i] = bbase[i] + hist[i * CHK + m];
  __syncthreads();
  long b0 = (long)m * E / CHK, b1 = (long)(m + 1) * E / CHK;
  for (long i = b0 + threadIdx.x; i < b1; i += TPB){
    int d = __builtin_nontemporal_load(&dst[i]);
    int s = __builtin_nontemporal_load(&src[i]);
    int b = d / nper;
    int dl = d - b * nper;
    int pos = atomicAdd(&offs[b], 1);
    bucketed[pos] = (dl << 17) | s;
  }
}

// pass 4: one block per bucket: per-node counts -> dinv + row_ptr (coalesced),
// then in-bucket placement (entire ~25KB csr region written by this block).
__global__ __launch_bounds__(TPB) void bucket_csr(const int* __restrict__ bucketed, const int* __restrict__ bbase,
                                                  int* __restrict__ csr, int* __restrict__ row_ptr,
                                                  float* __restrict__ dinv, int N, int E, int nper){
  int b = blockIdx.x;
  int base = bbase[b];
  int nE = bbase[b + 1] - base;
  int nodeBase = b * nper;
  int nn = N - nodeBase; if (nn > nper) nn = nper; if (nn < 0) nn = 0;

  __shared__ int packs[CAP];
  __shared__ int cnt[512];
  __shared__ int pref[512];

  for (int i = threadIdx.x; i < nn; i += TPB) cnt[i] = 0;
  __syncthreads();
  for (int i = threadIdx.x; i < nE; i += TPB){
    int p = bucketed[base + i];
    if (i < CAP) packs[i] = p;
    atomicAdd(&cnt[p >> 17], 1);
  }
  __syncthreads();
  // exclusive scan of cnt[0..nn) by wave 0 (64-wide segments with carry)
  if (threadIdx.x < 64){
    int carry = 0;
    for (int i0 = 0; i0 < nn; i0 += 64){
      int idx = i0 + threadIdx.x;
      int v = (idx < nn) ? cnt[idx] : 0;
      int x = v;
      #pragma unroll
      for (int off = 1; off < 64; off <<= 1){
        int y = __shfl_up(x, off);
        if (threadIdx.x >= off) x += y;
      }
      if (idx < nn) pref[idx] = carry + x - v;
      carry += __shfl(x, 63);
    }
  }
  __syncthreads();
  for (int i = threadIdx.x; i < nn; i += TPB){
    row_ptr[nodeBase + i] = base + pref[i];
    dinv[nodeBase + i] = rsqrtf((float)cnt[i] + 2.0f);
  }
  if (b == BKT - 1 && threadIdx.x == 0) row_ptr[N] = E;
  for (int i = threadIdx.x; i < nn; i += TPB) cnt[i] = 0;
  __syncthreads();
  for (int i = threadIdx.x; i < nE; i += TPB){
    int p = (i < CAP) ? packs[i] : bucketed[base + i];
    int dl = p >> 17;
    int r = atomicAdd(&cnt[dl], 1);
    csr[base + pref[dl] + r] = p & 131071;
  }
}

// ---------------- W split/transpose: fp32 -> bf16 hi/lo, transposed [col][k] ----------------

__global__ __launch_bounds__(TPB) void convW_all(const float* __restrict__ W0, const float* __restrict__ W1,
                                                 const float* __restrict__ W2, const float* __restrict__ W3,
                                                 unsigned short* __restrict__ Wh, unsigned short* __restrict__ Wl){
  int gid = blockIdx.x * TPB + threadIdx.x;
  if (gid < 3*16384){
    int which = gid >> 14, idx = gid & 16383;
    int c = idx >> 7, k = idx & 127;
    const float* W = (which == 0) ? W0 : (which == 1) ? W1 : W2;
    float f = W[k*128 + c];
    unsigned short h = f2bf(f);
    unsigned short l = f2bf(f - bf2f(h));
    Wh[gid] = h; Wl[gid] = l;
  } else if (gid < 3*16384 + 48*128){
    int idx = gid - 3*16384;
    int c = idx >> 7, k = idx & 127;
    float f = (c < 40) ? W3[k*40 + c] : 0.f;
    unsigned short h = f2bf(f);
    unsigned short l = f2bf(f - bf2f(h));
    Wh[gid] = h; Wl[gid] = l;
  }
}

// ---------------- MFMA GEMM: C[N x NC] = A[N x 128] @ W[128 x NC] (+bias) ----------------

template<int NCT, int NC, bool BIAS, typename CT>
__global__ __launch_bounds__(TPB) void gemm_mfma(const float* __restrict__ A,
                                                 const unsigned short* __restrict__ Wh,
                                                 const unsigned short* __restrict__ Wl,
                                                 const float* __restrict__ bias,
                                                 CT* __restrict__ C, int n){
  int wave = threadIdx.x >> 6;
  int lane = threadIdx.x & 63;
  int q    = lane >> 4;
  int m16  = lane & 15;
  int r0   = blockIdx.x * 128 + wave * 32;

  f32x4 acc[2][NCT];
  #pragma unroll
  for (int rt = 0; rt < 2; ++rt)
    #pragma unroll
    for (int ct = 0; ct < NCT; ++ct)
      acc[rt][ct] = (f32x4){0.f, 0.f, 0.f, 0.f};

  for (int k0 = 0; k0 < 128; k0 += 32){
    bf16x8 ah[2], al[2];
    #pragma unroll
    for (int rt = 0; rt < 2; ++rt){
      int r = r0 + rt*16 + m16;
      if (r > n-1) r = n-1;
      const float* ap = A + (size_t)r*128 + k0 + q*8;
      float4 f0 = *(const float4*)(ap);
      float4 f1 = *(const float4*)(ap + 4);
      float fv[8] = {f0.x, f0.y, f0.z, f0.w, f1.x, f1.y, f1.z, f1.w};
      #pragma unroll
      for (int j = 0; j < 8; ++j){
        unsigned short h = f2bf(fv[j]);
        unsigned short l = f2bf(fv[j] - bf2f(h));
        ah[rt][j] = (short)h;
        al[rt][j] = (short)l;
      }
    }
    #pragma unroll
    for (int ct = 0; ct < NCT; ++ct){
      int c = ct*16 + m16;
      const unsigned short* ph = Wh + (size_t)c*128 + k0 + q*8;
      const unsigned short* pl = Wl + (size_t)c*128 + k0 + q*8;
      bf16x8 bh = *(const bf16x8*)ph;
      bf16x8 bl = *(const bf16x8*)pl;
      #pragma unroll
      for (int rt = 0; rt < 2; ++rt){
        acc[rt][ct] = __builtin_amdgcn_mfma_f32_16x16x32_bf16(ah[rt], bh, acc[rt][ct], 0, 0, 0);
        acc[rt][ct] = __builtin_amdgcn_mfma_f32_16x16x32_bf16(ah[rt], bl, acc[rt][ct], 0, 0, 0);
        acc[rt][ct] = __builtin_amdgcn_mfma_f32_16x16x32_bf16(al[rt], bh, acc[rt][ct], 0, 0, 0);
      }
    }
  }
  #pragma unroll
  for (int rt = 0; rt < 2; ++rt){
    #pragma unroll
    for (int ct = 0; ct < NCT; ++ct){
      int c = ct*16 + m16;
      if (c < NC){
        float bv = BIAS ? bias[c] : 0.f;
        #pragma unroll
        for (int i = 0; i < 4; ++i){
          int r = r0 + rt*16 + q*4 + i;
          if (r < n) C[(size_t)r*NC + c] = (CT)(acc[rt][ct][i] + bv);
        }
      }
    }
  }
}

// ---------------- Aggregation: 16 lanes per dst node, 8 fp16 feats (16 B) per lane ----------------

template<int MODE, bool OUTH>
__global__ __launch_bounds__(TPB) void agg_h(const __half* __restrict__ xh, const float* __restrict__ resf,
                                             const float* __restrict__ dinv, const int* __restrict__ row_ptr,
                                             const int* __restrict__ csr_src, const float* __restrict__ bias,
                                             void* __restrict__ outp, int n){
  int g = (int)((blockIdx.x * (unsigned)TPB + threadIdx.x) >> 4);
  if (g >= n) return;
  int lane = threadIdx.x & 15;
  float di = dinv[g];
  int beg = row_ptr[g], end = row_ptr[g+1];

  float accA[8], accB[8];
  #pragma unroll
  for (int i = 0; i < 8; ++i){ accA[i] = 0.f; accB[i] = 0.f; }

  for (int base = beg; base < end; base += 16){
    int m = end - base; if (m > 16) m = 16;
    int   sl = (lane < m) ? csr_src[base + lane] : 0;
    float cl = (lane < m) ? dinv[sl] * di : 0.f;
    int mm = (m + 1) & ~1;
    for (int j = 0; j < mm; j += 2){
      int   s0 = __shfl(sl, j,   16), s1 = __shfl(sl, j+1, 16);
      float c0 = __shfl(cl, j,   16), c1 = __shfl(cl, j+1, 16);
      uint4 u0 = *(const uint4*)(xh + (size_t)s0 * 128 + lane * 8);
      uint4 u1 = *(const uint4*)(xh + (size_t)s1 * 128 + lane * 8);
      const __half2* h0 = (const __half2*)&u0;
      const __half2* h1 = (const __half2*)&u1;
      #pragma unroll
      for (int i = 0; i < 4; ++i){
        float2 f0 = __half22float2(h0[i]);
        float2 f1 = __half22float2(h1[i]);
        accA[2*i]   = fmaf(c0, f0.x, accA[2*i]);
        accA[2*i+1] = fmaf(c0, f0.y, accA[2*i+1]);
        accB[2*i]   = fmaf(c1, f1.x, accB[2*i]);
        accB[2*i+1] = fmaf(c1, f1.y, accB[2*i+1]);
      }
    }
  }
  // self loop
  {
    float sc = 2.0f * di * di;
    uint4 u = *(const uint4*)(xh + (size_t)g * 128 + lane * 8);
    const __half2* h = (const __half2*)&u;
    #pragma unroll
    for (int i = 0; i < 4; ++i){
      float2 f = __half22float2(h[i]);
      accA[2*i]   = fmaf(sc, f.x, accA[2*i]);
      accA[2*i+1] = fmaf(sc, f.y, accA[2*i+1]);
    }
  }
  #pragma unroll
  for (int i = 0; i < 8; ++i) accA[i] += accB[i];

  if (MODE != 2){
    float4 b0 = *(const float4*)(bias + lane*8);
    float4 b1 = *(const float4*)(bias + lane*8 + 4);
    accA[0]+=b0.x; accA[1]+=b0.y; accA[2]+=b0.z; accA[3]+=b0.w;
    accA[4]+=b1.x; accA[5]+=b1.y; accA[6]+=b1.z; accA[7]+=b1.w;
  }
  if (MODE == 1){
    float4 r0 = *(const float4*)(resf + (size_t)g*128 + lane*8);
    float4 r1 = *(const float4*)(resf + (size_t)g*128 + lane*8 + 4);
    accA[0]+=r0.x; accA[1]+=r0.y; accA[2]+=r0.z; accA[3]+=r0.w;
    accA[4]+=r1.x; accA[5]+=r1.y; accA[6]+=r1.z; accA[7]+=r1.w;
  }
  if (MODE != 2){
    #pragma unroll
    for (int i = 0; i < 8; ++i) accA[i] = gelu_erf(accA[i]);
  }
  if (OUTH){
    __half hv[8];
    #pragma unroll
    for (int i = 0; i < 8; ++i) hv[i] = __float2half(accA[i]);
    *(uint4*)((__half*)outp + (size_t)g*128 + lane*8) = *(const uint4*)hv;
  } else {
    float* op = (float*)outp + (size_t)g*128 + lane*8;
    *(float4*)op       = make_float4(accA[0],accA[1],accA[2],accA[3]);
    *(float4*)(op + 4) = make_float4(accA[4],accA[5],accA[6],accA[7]);
  }
}

// ---------------- launch ----------------

extern "C" void kernel_launch(void* const* d_in, const int* in_sizes, int n_in,
                              void* d_out, int out_size, void* d_ws, size_t ws_size,
                              hipStream_t stream){
  const float* x  = (const float*)d_in[0];
  const int*   ei = (const int*)d_in[1];
  const float* W0 = (const float*)d_in[2];
  const float* b0 = (const float*)d_in[3];
  const float* W1 = (const float*)d_in[4];
  const float* b1 = (const float*)d_in[5];
  const float* W2 = (const float*)d_in[6];
  const float* b2 = (const float*)d_in[7];
  const float* W3 = (const float*)d_in[8];
  const float* b3 = (const float*)d_in[9];
  float* out = (float*)d_out;

  const int N = in_sizes[0] / 128;
  const int E = in_sizes[1] / 2;
  const int* src = ei;
  const int* dst = ei + E;
  const int nper = (N + BKT - 1) / BKT;   // nodes per bucket (391)

  char* ws = (char*)d_ws;
  size_t off = 0;
  auto alloc = [&](size_t bytes) -> void* {
    void* p = ws + off;
    off += (bytes + 255) & ~(size_t)255;
    return p;
  };
  __half* xw_h  = (__half*)alloc((size_t)N * 128 * 2);
  float*  gA    = (float*) alloc((size_t)N * 128 * 4);
  float*  gB    = (float*) alloc((size_t)N * 128 * 4);
  __half* gAh   = (__half*)alloc((size_t)N * 128 * 2);
  int* csr      = (int*)   alloc((size_t)E * 4);
  int* bucketed = (int*)   alloc((size_t)E * 4);
  int* row_ptr  = (int*)   alloc((size_t)(N + 1) * 4);
  float* dnv    = (float*) alloc((size_t)N * 4);
  int* hist     = (int*)   alloc((size_t)BKT * CHK * 4);
  int* btot     = (int*)   alloc((size_t)BKT * 4);
  int* bbase    = (int*)   alloc((size_t)(BKT + 1) * 4);
  const int WTOT = 3*16384 + 48*128;
  unsigned short* Wh = (unsigned short*)alloc((size_t)WTOT * 2);
  unsigned short* Wl = (unsigned short*)alloc((size_t)WTOT * 2);
  (void)ws_size; (void)n_in; (void)out_size;

  convW_all<<<(WTOT + TPB - 1)/TPB, TPB, 0, stream>>>(W0, W1, W2, W3, Wh, Wl);
  hist_kernel<<<CHK, TPB, 0, stream>>>(dst, hist, E, nper);
  scanA<<<BKT, CHK, 0, stream>>>(hist, btot);
  scanB<<<1, BKT, 0, stream>>>(btot, bbase, E);
  bucket_scatter<<<CHK, TPB, 0, stream>>>(src, dst, hist, bbase, bucketed, E, nper);
  bucket_csr<<<BKT, TPB, 0, stream>>>(bucketed, bbase, csr, row_ptr, dnv, N, E, nper);

  int gblocks = (N + 127) / 128;
  int ablocks = ((size_t)N * 16 + TPB - 1) / TPB;

  const unsigned short* W0h = Wh,          *W0l = Wl;
  const unsigned short* W1h = Wh + 16384,  *W1l = Wl + 16384;
  const unsigned short* W2h = Wh + 32768,  *W2l = Wl + 32768;
  const unsigned short* W3h = Wh + 49152,  *W3l = Wl + 49152;

  // L0: gA = gelu(conv(x))
  gemm_mfma<8,128,false,__half><<<gblocks, TPB, 0, stream>>>(x, W0h, W0l, nullptr, xw_h, N);
  agg_h<0,false><<<ablocks, TPB, 0, stream>>>(xw_h, nullptr, dnv, row_ptr, csr, b0, gA, N);
  // L1: gB = gelu(gA + conv(gA))
  gemm_mfma<8,128,false,__half><<<gblocks, TPB, 0, stream>>>(gA, W1h, W1l, nullptr, xw_h, N);
  agg_h<1,false><<<ablocks, TPB, 0, stream>>>(xw_h, gA, dnv, row_ptr, csr, b1, gB, N);
  // L2: gAh = gelu(gB + conv(gB))  (fp16 out, feeds gather-only consumer)
  gemm_mfma<8,128,false,__half><<<gblocks, TPB, 0, stream>>>(gB, W2h, W2l, nullptr, xw_h, N);
  agg_h<1,true><<<ablocks, TPB, 0, stream>>>(xw_h, gB, dnv, row_ptr, csr, b2, gAh, N);
  // L3: out = Agg(gAh) @ W3 + b3
  agg_h<2,false><<<ablocks, TPB, 0, stream>>>(gAh, nullptr, dnv, row_ptr, csr, nullptr, gA, N);
  gemm_mfma<3,40,true,float><<<gblocks, TPB, 0, stream>>>(gA, W3h, W3l, b3, out, N);
}

// Round 9
// 560.513 us; speedup vs baseline: 1.4080x; 1.0575x over previous
//
#include <hip/hip_runtime.h>
#include <hip/hip_fp16.h>
#include <math.h>
#include <type_traits>

#define TPB 256
#define BKT 256     // dst buckets
#define CHK 256     // edge chunks
#define CAP 12288   // LDS edge cache per bucket (avg 6250 for E=1.6M)

typedef short  bf16x8 __attribute__((ext_vector_type(8)));
typedef float  f32x4  __attribute__((ext_vector_type(4)));

__device__ __forceinline__ float gelu_erf(float x){
  return 0.5f * x * (1.0f + erff(x * 0.70710678118654752440f));
}

__device__ __forceinline__ unsigned short f2bf(float f){
  union { float f; unsigned u; } v; v.f = f;
  unsigned r = v.u + 0x7fff + ((v.u >> 16) & 1);
  return (unsigned short)(r >> 16);
}
__device__ __forceinline__ float bf2f(unsigned short h){
  union { unsigned u; float f; } v; v.u = ((unsigned)h) << 16; return v.f;
}

// ---------------- prep: hist (blocks 0..CHK-1) + W split (blocks >= CHK) ----------------

__global__ __launch_bounds__(TPB) void prep_kernel(const int* __restrict__ dst, int* __restrict__ hist,
                                                   const float* __restrict__ W0, const float* __restrict__ W1,
                                                   const float* __restrict__ W2, const float* __restrict__ W3,
                                                   unsigned short* __restrict__ Wh, unsigned short* __restrict__ Wl,
                                                   int E, int nper){
  if (blockIdx.x < CHK){
    __shared__ int h[BKT];
    for (int i = threadIdx.x; i < BKT; i += TPB) h[i] = 0;
    __syncthreads();
    int m = blockIdx.x;
    long b0 = (long)m * E / CHK, b1 = (long)(m + 1) * E / CHK;
    for (long i = b0 + threadIdx.x; i < b1; i += TPB){
      int d = __builtin_nontemporal_load(&dst[i]);
      atomicAdd(&h[d / nper], 1);
    }
    __syncthreads();
    for (int i = threadIdx.x; i < BKT; i += TPB) hist[i * CHK + m] = h[i];
  } else {
    int gid = (blockIdx.x - CHK) * TPB + threadIdx.x;
    if (gid < 3*16384){
      int which = gid >> 14, idx = gid & 16383;
      int c = idx >> 7, k = idx & 127;
      const float* W = (which == 0) ? W0 : (which == 1) ? W1 : W2;
      float f = W[k*128 + c];
      unsigned short h = f2bf(f);
      unsigned short l = f2bf(f - bf2f(h));
      Wh[gid] = h; Wl[gid] = l;
    } else if (gid < 3*16384 + 48*128){
      int idx = gid - 3*16384;
      int c = idx >> 7, k = idx & 127;
      float f = (c < 40) ? W3[k*40 + c] : 0.f;
      unsigned short h = f2bf(f);
      unsigned short l = f2bf(f - bf2f(h));
      Wh[gid] = h; Wl[gid] = l;
    }
  }
}

// per-bucket exclusive scan over chunks; bucket totals -> btot
__global__ __launch_bounds__(CHK) void scanA(int* __restrict__ hist, int* __restrict__ btot){
  __shared__ int tmp[CHK];
  int b = blockIdx.x, t = threadIdx.x;
  int v = hist[b * CHK + t];
  int x = v;
  tmp[t] = x;
  __syncthreads();
  #pragma unroll
  for (int off = 1; off < CHK; off <<= 1){
    int y = (t >= off) ? tmp[t - off] : 0;
    __syncthreads();
    x += y;
    tmp[t] = x;
    __syncthreads();
  }
  hist[b * CHK + t] = x - v;
  if (t == CHK - 1) btot[b] = x;
}

// scatter edges into bucket-contiguous runs, packed (dst_local<<17)|src.
// bucket bases computed locally from btot (inline scan) -> no scanB dispatch.
__global__ __launch_bounds__(TPB) void bucket_scatter(const int* __restrict__ src, const int* __restrict__ dst,
                                                      const int* __restrict__ hist, const int* __restrict__ btot,
                                                      int* __restrict__ bucketed, int E, int nper){
  __shared__ int offs[BKT];
  __shared__ int tmp[BKT];
  int m = blockIdx.x;
  int t = threadIdx.x;
  {
    int v = btot[t];
    int x = v;
    tmp[t] = x;
    __syncthreads();
    #pragma unroll
    for (int off = 1; off < BKT; off <<= 1){
      int y = (t >= off) ? tmp[t - off] : 0;
      __syncthreads();
      x += y;
      tmp[t] = x;
      __syncthreads();
    }
    offs[t] = (x - v) + hist[t * CHK + m];
    __syncthreads();
  }
  long b0 = (long)m * E / CHK, b1 = (long)(m + 1) * E / CHK;
  for (long i = b0 + threadIdx.x; i < b1; i += TPB){
    int d = __builtin_nontemporal_load(&dst[i]);
    int s = __builtin_nontemporal_load(&src[i]);
    int b = d / nper;
    int dl = d - b * nper;
    int pos = atomicAdd(&offs[b], 1);
    bucketed[pos] = (dl << 17) | s;
  }
}

// one block per bucket: per-node counts -> dinv + row_ptr, then in-bucket CSR placement.
__global__ __launch_bounds__(TPB) void bucket_csr(const int* __restrict__ bucketed, const int* __restrict__ btot,
                                                  int* __restrict__ csr, int* __restrict__ row_ptr,
                                                  float* __restrict__ dinv, int N, int E, int nper){
  int b = blockIdx.x;
  int t = threadIdx.x;
  __shared__ int packs[CAP];
  __shared__ int cnt[512];
  __shared__ int pref[512];
  __shared__ int tmp[BKT];
  __shared__ int sBase, sNE;
  {
    int v = btot[t];
    int x = v;
    tmp[t] = x;
    __syncthreads();
    #pragma unroll
    for (int off = 1; off < BKT; off <<= 1){
      int y = (t >= off) ? tmp[t - off] : 0;
      __syncthreads();
      x += y;
      tmp[t] = x;
      __syncthreads();
    }
    if (t == b){ sBase = x - v; sNE = v; }
    __syncthreads();
  }
  int base = sBase;
  int nE = sNE;
  int nodeBase = b * nper;
  int nn = N - nodeBase; if (nn > nper) nn = nper; if (nn < 0) nn = 0;

  for (int i = t; i < nn; i += TPB) cnt[i] = 0;
  __syncthreads();
  for (int i = t; i < nE; i += TPB){
    int p = bucketed[base + i];
    if (i < CAP) packs[i] = p;
    atomicAdd(&cnt[p >> 17], 1);
  }
  __syncthreads();
  if (t < 64){
    int carry = 0;
    for (int i0 = 0; i0 < nn; i0 += 64){
      int idx = i0 + t;
      int v = (idx < nn) ? cnt[idx] : 0;
      int x = v;
      #pragma unroll
      for (int off = 1; off < 64; off <<= 1){
        int y = __shfl_up(x, off);
        if (t >= off) x += y;
      }
      if (idx < nn) pref[idx] = carry + x - v;
      carry += __shfl(x, 63);
    }
  }
  __syncthreads();
  for (int i = t; i < nn; i += TPB){
    row_ptr[nodeBase + i] = base + pref[i];
    dinv[nodeBase + i] = rsqrtf((float)cnt[i] + 2.0f);
  }
  if (b == BKT - 1 && t == 0) row_ptr[N] = E;
  for (int i = t; i < nn; i += TPB) cnt[i] = 0;
  __syncthreads();
  for (int i = t; i < nE; i += TPB){
    int p = (i < CAP) ? packs[i] : bucketed[base + i];
    int dl = p >> 17;
    int r = atomicAdd(&cnt[dl], 1);
    csr[base + pref[dl] + r] = p & 131071;
  }
}

// ---------------- MFMA GEMM: C[N x NC] = A[N x 128] @ W[128 x NC] (+bias) ----------------
// AT = float (fp32 input, in-register bf16 hi/lo split) or __half (exact 2-term split).

template<int NCT, int NC, bool BIAS, typename AT, typename CT>
__global__ __launch_bounds__(TPB) void gemm_mfma(const AT* __restrict__ A,
                                                 const unsigned short* __restrict__ Wh,
                                                 const unsigned short* __restrict__ Wl,
                                                 const float* __restrict__ bias,
                                                 CT* __restrict__ C, int n){
  int wave = threadIdx.x >> 6;
  int lane = threadIdx.x & 63;
  int q    = lane >> 4;
  int m16  = lane & 15;
  int r0   = blockIdx.x * 128 + wave * 32;

  f32x4 acc[2][NCT];
  #pragma unroll
  for (int rt = 0; rt < 2; ++rt)
    #pragma unroll
    for (int ct = 0; ct < NCT; ++ct)
      acc[rt][ct] = (f32x4){0.f, 0.f, 0.f, 0.f};

  for (int k0 = 0; k0 < 128; k0 += 32){
    bf16x8 ah[2], al[2];
    #pragma unroll
    for (int rt = 0; rt < 2; ++rt){
      int r = r0 + rt*16 + m16;
      if (r > n-1) r = n-1;
      const AT* ap = A + (size_t)r*128 + k0 + q*8;
      float fv[8];
      if constexpr (std::is_same<AT, float>::value){
        float4 f0 = *(const float4*)(ap);
        float4 f1 = *(const float4*)(ap + 4);
        fv[0]=f0.x; fv[1]=f0.y; fv[2]=f0.z; fv[3]=f0.w;
        fv[4]=f1.x; fv[5]=f1.y; fv[6]=f1.z; fv[7]=f1.w;
      } else {
        uint4 u = *(const uint4*)(ap);
        const __half2* hp = (const __half2*)&u;
        #pragma unroll
        for (int i = 0; i < 4; ++i){
          float2 f = __half22float2(hp[i]);
          fv[2*i] = f.x; fv[2*i+1] = f.y;
        }
      }
      #pragma unroll
      for (int j = 0; j < 8; ++j){
        unsigned short h = f2bf(fv[j]);
        unsigned short l = f2bf(fv[j] - bf2f(h));
        ah[rt][j] = (short)h;
        al[rt][j] = (short)l;
      }
    }
    #pragma unroll
    for (int ct = 0; ct < NCT; ++ct){
      int c = ct*16 + m16;
      const unsigned short* ph = Wh + (size_t)c*128 + k0 + q*8;
      const unsigned short* pl = Wl + (size_t)c*128 + k0 + q*8;
      bf16x8 bh = *(const bf16x8*)ph;
      bf16x8 bl = *(const bf16x8*)pl;
      #pragma unroll
      for (int rt = 0; rt < 2; ++rt){
        acc[rt][ct] = __builtin_amdgcn_mfma_f32_16x16x32_bf16(ah[rt], bh, acc[rt][ct], 0, 0, 0);
        acc[rt][ct] = __builtin_amdgcn_mfma_f32_16x16x32_bf16(ah[rt], bl, acc[rt][ct], 0, 0, 0);
        acc[rt][ct] = __builtin_amdgcn_mfma_f32_16x16x32_bf16(al[rt], bh, acc[rt][ct], 0, 0, 0);
      }
    }
  }
  #pragma unroll
  for (int rt = 0; rt < 2; ++rt){
    #pragma unroll
    for (int ct = 0; ct < NCT; ++ct){
      int c = ct*16 + m16;
      if (c < NC){
        float bv = BIAS ? bias[c] : 0.f;
        #pragma unroll
        for (int i = 0; i < 4; ++i){
          int r = r0 + rt*16 + q*4 + i;
          if (r < n) C[(size_t)r*NC + c] = (CT)(acc[rt][ct][i] + bv);
        }
      }
    }
  }
}

// ---------------- Aggregation: 16 lanes per dst node, 8 fp16 feats (16 B) per lane ----------------
// MODE 0: out = gelu(agg + self + bias);  MODE 1: + res;  MODE 2: out = agg + self.
// All feature streams fp16 (res too); accumulate fp32.

template<int MODE>
__global__ __launch_bounds__(TPB) void agg_h(const __half* __restrict__ xh, const __half* __restrict__ resh,
                                             const float* __restrict__ dinv, const int* __restrict__ row_ptr,
                                             const int* __restrict__ csr_src, const float* __restrict__ bias,
                                             __half* __restrict__ outp, int n){
  int g = (int)((blockIdx.x * (unsigned)TPB + threadIdx.x) >> 4);
  if (g >= n) return;
  int lane = threadIdx.x & 15;
  float di = dinv[g];
  int beg = row_ptr[g], end = row_ptr[g+1];

  float accA[8], accB[8];
  #pragma unroll
  for (int i = 0; i < 8; ++i){ accA[i] = 0.f; accB[i] = 0.f; }

  for (int base = beg; base < end; base += 16){
    int m = end - base; if (m > 16) m = 16;
    int   sl = (lane < m) ? csr_src[base + lane] : 0;
    float cl = (lane < m) ? dinv[sl] * di : 0.f;
    int mm = (m + 1) & ~1;
    for (int j = 0; j < mm; j += 2){
      int   s0 = __shfl(sl, j,   16), s1 = __shfl(sl, j+1, 16);
      float c0 = __shfl(cl, j,   16), c1 = __shfl(cl, j+1, 16);
      uint4 u0 = *(const uint4*)(xh + (size_t)s0 * 128 + lane * 8);
      uint4 u1 = *(const uint4*)(xh + (size_t)s1 * 128 + lane * 8);
      const __half2* h0 = (const __half2*)&u0;
      const __half2* h1 = (const __half2*)&u1;
      #pragma unroll
      for (int i = 0; i < 4; ++i){
        float2 f0 = __half22float2(h0[i]);
        float2 f1 = __half22float2(h1[i]);
        accA[2*i]   = fmaf(c0, f0.x, accA[2*i]);
        accA[2*i+1] = fmaf(c0, f0.y, accA[2*i+1]);
        accB[2*i]   = fmaf(c1, f1.x, accB[2*i]);
        accB[2*i+1] = fmaf(c1, f1.y, accB[2*i+1]);
      }
    }
  }
  // self loop
  {
    float sc = 2.0f * di * di;
    uint4 u = *(const uint4*)(xh + (size_t)g * 128 + lane * 8);
    const __half2* h = (const __half2*)&u;
    #pragma unroll
    for (int i = 0; i < 4; ++i){
      float2 f = __half22float2(h[i]);
      accA[2*i]   = fmaf(sc, f.x, accA[2*i]);
      accA[2*i+1] = fmaf(sc, f.y, accA[2*i+1]);
    }
  }
  #pragma unroll
  for (int i = 0; i < 8; ++i) accA[i] += accB[i];

  if (MODE != 2){
    float4 b0 = *(const float4*)(bias + lane*8);
    float4 b1 = *(const float4*)(bias + lane*8 + 4);
    accA[0]+=b0.x; accA[1]+=b0.y; accA[2]+=b0.z; accA[3]+=b0.w;
    accA[4]+=b1.x; accA[5]+=b1.y; accA[6]+=b1.z; accA[7]+=b1.w;
  }
  if (MODE == 1){
    uint4 ur = *(const uint4*)(resh + (size_t)g*128 + lane*8);
    const __half2* hr = (const __half2*)&ur;
    #pragma unroll
    for (int i = 0; i < 4; ++i){
      float2 f = __half22float2(hr[i]);
      accA[2*i]   += f.x;
      accA[2*i+1] += f.y;
    }
  }
  if (MODE != 2){
    #pragma unroll
    for (int i = 0; i < 8; ++i) accA[i] = gelu_erf(accA[i]);
  }
  __half hv[8];
  #pragma unroll
  for (int i = 0; i < 8; ++i) hv[i] = __float2half(accA[i]);
  *(uint4*)(outp + (size_t)g*128 + lane*8) = *(const uint4*)hv;
}

// ---------------- launch ----------------

extern "C" void kernel_launch(void* const* d_in, const int* in_sizes, int n_in,
                              void* d_out, int out_size, void* d_ws, size_t ws_size,
                              hipStream_t stream){
  const float* x  = (const float*)d_in[0];
  const int*   ei = (const int*)d_in[1];
  const float* W0 = (const float*)d_in[2];
  const float* b0 = (const float*)d_in[3];
  const float* W1 = (const float*)d_in[4];
  const float* b1 = (const float*)d_in[5];
  const float* W2 = (const float*)d_in[6];
  const float* b2 = (const float*)d_in[7];
  const float* W3 = (const float*)d_in[8];
  const float* b3 = (const float*)d_in[9];
  float* out = (float*)d_out;

  const int N = in_sizes[0] / 128;
  const int E = in_sizes[1] / 2;
  const int* src = ei;
  const int* dst = ei + E;
  const int nper = (N + BKT - 1) / BKT;   // nodes per bucket (391)

  char* ws = (char*)d_ws;
  size_t off = 0;
  auto alloc = [&](size_t bytes) -> void* {
    void* p = ws + off;
    off += (bytes + 255) & ~(size_t)255;
    return p;
  };
  __half* xw_h  = (__half*)alloc((size_t)N * 128 * 2);
  __half* g0    = (__half*)alloc((size_t)N * 128 * 2);
  __half* g1    = (__half*)alloc((size_t)N * 128 * 2);
  __half* g2    = (__half*)alloc((size_t)N * 128 * 2);
  int* csr      = (int*)   alloc((size_t)E * 4);
  int* bucketed = (int*)   alloc((size_t)E * 4);
  int* row_ptr  = (int*)   alloc((size_t)(N + 1) * 4);
  float* dnv    = (float*) alloc((size_t)N * 4);
  int* hist     = (int*)   alloc((size_t)BKT * CHK * 4);
  int* btot     = (int*)   alloc((size_t)BKT * 4);
  const int WTOT = 3*16384 + 48*128;
  unsigned short* Wh = (unsigned short*)alloc((size_t)WTOT * 2);
  unsigned short* Wl = (unsigned short*)alloc((size_t)WTOT * 2);
  (void)ws_size; (void)n_in; (void)out_size;

  const int WB = (WTOT + TPB - 1) / TPB;
  prep_kernel<<<CHK + WB, TPB, 0, stream>>>(dst, hist, W0, W1, W2, W3, Wh, Wl, E, nper);
  scanA<<<BKT, CHK, 0, stream>>>(hist, btot);
  bucket_scatter<<<CHK, TPB, 0, stream>>>(src, dst, hist, btot, bucketed, E, nper);
  bucket_csr<<<BKT, TPB, 0, stream>>>(bucketed, btot, csr, row_ptr, dnv, N, E, nper);

  int gblocks = (N + 127) / 128;
  int ablocks = ((size_t)N * 16 + TPB - 1) / TPB;

  const unsigned short* W0h = Wh,          *W0l = Wl;
  const unsigned short* W1h = Wh + 16384,  *W1l = Wl + 16384;
  const unsigned short* W2h = Wh + 32768,  *W2l = Wl + 32768;
  const unsigned short* W3h = Wh + 49152,  *W3l = Wl + 49152;

  // L0: g0 = gelu(conv(x))
  gemm_mfma<8,128,false,float,__half><<<gblocks, TPB, 0, stream>>>(x, W0h, W0l, nullptr, xw_h, N);
  agg_h<0><<<ablocks, TPB, 0, stream>>>(xw_h, nullptr, dnv, row_ptr, csr, b0, g0, N);
  // L1: g1 = gelu(g0 + conv(g0))
  gemm_mfma<8,128,false,__half,__half><<<gblocks, TPB, 0, stream>>>(g0, W1h, W1l, nullptr, xw_h, N);
  agg_h<1><<<ablocks, TPB, 0, stream>>>(xw_h, g0, dnv, row_ptr, csr, b1, g1, N);
  // L2: g2 = gelu(g1 + conv(g1))
  gemm_mfma<8,128,false,__half,__half><<<gblocks, TPB, 0, stream>>>(g1, W2h, W2l, nullptr, xw_h, N);
  agg_h<1><<<ablocks, TPB, 0, stream>>>(xw_h, g1, dnv, row_ptr, csr, b2, g2, N);
  // L3: out = Agg(g2) @ W3 + b3   (Agg commutes with right-multiplication)
  agg_h<2><<<ablocks, TPB, 0, stream>>>(g2, nullptr, dnv, row_ptr, csr, nullptr, xw_h, N);
  gemm_mfma<3,40,true,__half,float><<<gblocks, TPB, 0, stream>>>(xw_h, W3h, W3l, b3, out, N);
}

// Round 11
// 550.878 us; speedup vs baseline: 1.4326x; 1.0175x over previous
//
#include <hip/hip_runtime.h>
#include <hip/hip_fp16.h>
#include <math.h>
#include <type_traits>

#define TPB  256
#define BKT  256     // dst buckets
#define CHK  256     // edge chunks
#define BCAP 12288   // padded capacity per bucket (avg 6250, >5 sigma headroom)
#define CMAX 6656    // LDS edge-chunk stage

typedef short  bf16x8 __attribute__((ext_vector_type(8)));
typedef float  f32x4  __attribute__((ext_vector_type(4)));

__device__ __forceinline__ float gelu_erf(float x){
  return 0.5f * x * (1.0f + erff(x * 0.70710678118654752440f));
}
__device__ __forceinline__ unsigned short f2bf(float f){
  union { float f; unsigned u; } v; v.f = f;
  unsigned r = v.u + 0x7fff + ((v.u >> 16) & 1);
  return (unsigned short)(r >> 16);
}
__device__ __forceinline__ float bf2f(unsigned short h){
  union { unsigned u; float f; } v; v.u = ((unsigned)h) << 16; return v.f;
}
// truncation split: f ~= bf16(h) + bf16(l), packed (h in low 16, l in high 16).
// Exact for fp16-sourced f; <=2^-15 rel for fp32.
__device__ __forceinline__ unsigned split_tr(float f){
  unsigned u = __float_as_uint(f);
  float r = f - __uint_as_float(u & 0xffff0000u);
  return (u >> 16) | (__float_as_uint(r) & 0xffff0000u);
}
__device__ __forceinline__ int divmagic(int d, unsigned long long inv){
  return (int)(((unsigned long long)(unsigned)d * inv) >> 40);
}

// ---------------- CSR build: 2 dispatches, padded buckets ----------------
// R8 counting sort proven (write locality by construction); R10 removes the
// hist/scanA passes: fixed-capacity buckets + per-block LDS count + one global
// reservation per (block,bucket). Blocks 0..CHK-1 scatter; blocks >=CHK split W.

__global__ __launch_bounds__(TPB) void prep_kernel(const int* __restrict__ src, const int* __restrict__ dst,
                                                   int* __restrict__ bcnt, int* __restrict__ bucketed,
                                                   const float* __restrict__ W0, const float* __restrict__ W1,
                                                   const float* __restrict__ W2, const float* __restrict__ W3,
                                                   unsigned short* __restrict__ Wh, unsigned short* __restrict__ Wl,
                                                   int E, int nper, unsigned long long inv){
  if (blockIdx.x < CHK){
    __shared__ int sdst[CMAX];
    __shared__ int ssrc[CMAX];
    __shared__ int lcnt[BKT];
    __shared__ int lbase[BKT];
    int m = blockIdx.x, t = threadIdx.x;
    long b0 = (long)m * E / CHK, b1 = (long)(m + 1) * E / CHK;
    for (long s0 = b0; s0 < b1; s0 += CMAX){
      int len = (int)((b1 - s0 < CMAX) ? (b1 - s0) : CMAX);
      for (int i = t; i < len; i += TPB){
        sdst[i] = __builtin_nontemporal_load(&dst[s0 + i]);
        ssrc[i] = __builtin_nontemporal_load(&src[s0 + i]);
      }
      lcnt[t] = 0;
      __syncthreads();
      for (int i = t; i < len; i += TPB) atomicAdd(&lcnt[divmagic(sdst[i], inv)], 1);
      __syncthreads();
      lbase[t] = atomicAdd(&bcnt[t], lcnt[t]);   // one reservation per (block,bucket)
      lcnt[t] = 0;
      __syncthreads();
      for (int i = t; i < len; i += TPB){
        int d = sdst[i];
        int b = divmagic(d, inv);
        int dl = d - b * nper;
        int r = lbase[b] + atomicAdd(&lcnt[b], 1);
        if (r < BCAP) bucketed[b * BCAP + r] = (dl << 17) | ssrc[i];
      }
      __syncthreads();
    }
  } else {
    int gid = (blockIdx.x - CHK) * TPB + threadIdx.x;
    if (gid < 3*16384){
      int which = gid >> 14, idx = gid & 16383;
      int c = idx >> 7, k = idx & 127;
      const float* W = (which == 0) ? W0 : (which == 1) ? W1 : W2;
      float f = W[k*128 + c];
      unsigned short h = f2bf(f);
      unsigned short l = f2bf(f - bf2f(h));
      Wh[gid] = h; Wl[gid] = l;
    } else if (gid < 3*16384 + 48*128){
      int idx = gid - 3*16384;
      int c = idx >> 7, k = idx & 127;
      float f = (c < 40) ? W3[k*40 + c] : 0.f;
      unsigned short h = f2bf(f);
      unsigned short l = f2bf(f - bf2f(h));
      Wh[gid] = h; Wl[gid] = l;
    }
  }
}

// one block per bucket: counts -> dinv + row_beg/row_end (padded csr), placement.
__global__ __launch_bounds__(TPB) void bucket_csr(const int* __restrict__ bucketed, const int* __restrict__ bcnt,
                                                  int* __restrict__ csr, int* __restrict__ row_beg,
                                                  int* __restrict__ row_end, float* __restrict__ dinv,
                                                  int N, int nper){
  int b = blockIdx.x, t = threadIdx.x;
  int base = b * BCAP;
  int nE = bcnt[b]; if (nE > BCAP) nE = BCAP;
  int nodeBase = b * nper;
  int nn = N - nodeBase; if (nn > nper) nn = nper; if (nn < 0) nn = 0;

  __shared__ int packs[BCAP];
  __shared__ int cnt[512];
  __shared__ int pref[512];

  for (int i = t; i < nn; i += TPB) cnt[i] = 0;
  __syncthreads();
  for (int i = t; i < nE; i += TPB){
    int p = bucketed[base + i];
    packs[i] = p;
    atomicAdd(&cnt[p >> 17], 1);
  }
  __syncthreads();
  if (t < 64){
    int carry = 0;
    for (int i0 = 0; i0 < nn; i0 += 64){
      int idx = i0 + t;
      int v = (idx < nn) ? cnt[idx] : 0;
      int x = v;
      #pragma unroll
      for (int off = 1; off < 64; off <<= 1){
        int y = __shfl_up(x, off);
        if (t >= off) x += y;
      }
      if (idx < nn) pref[idx] = carry + x - v;
      carry += __shfl(x, 63);
    }
  }
  __syncthreads();
  for (int i = t; i < nn; i += TPB){
    int beg = base + pref[i];
    row_beg[nodeBase + i] = beg;
    row_end[nodeBase + i] = beg + cnt[i];
    dinv[nodeBase + i] = rsqrtf((float)cnt[i] + 2.0f);
  }
  for (int i = t; i < nn; i += TPB) cnt[i] = 0;
  __syncthreads();
  for (int i = t; i < nE; i += TPB){
    int p = packs[i];
    int dl = p >> 17;
    int r = atomicAdd(&cnt[dl], 1);
    csr[base + pref[dl] + r] = p & 131071;
  }
}

// ---------------- MFMA GEMM: C[N x NC] = A[N x 128] @ W[128 x NC] (+bias) ----------------
// LDS-staged epilogue: MFMA C-layout -> LDS tile -> coalesced uint4 row writes
// (R9 epilogue was 64 scattered 2-byte stores per thread).

template<int NCT, int NC, bool BIAS, typename AT, typename CT>
__global__ __launch_bounds__(TPB) void gemm_mfma(const AT* __restrict__ A,
                                                 const unsigned short* __restrict__ Wh,
                                                 const unsigned short* __restrict__ Wl,
                                                 const float* __restrict__ bias,
                                                 CT* __restrict__ C, int n){
  constexpr int STR = NCT*16 + 8;                  // LDS row stride
  __shared__ CT Cs[128][STR];
  int wave = threadIdx.x >> 6;
  int lane = threadIdx.x & 63;
  int q    = lane >> 4;
  int m16  = lane & 15;
  int rb   = blockIdx.x * 128;
  int r0   = rb + wave * 32;

  f32x4 acc[2][NCT];
  #pragma unroll
  for (int rt = 0; rt < 2; ++rt)
    #pragma unroll
    for (int ct = 0; ct < NCT; ++ct)
      acc[rt][ct] = (f32x4){0.f, 0.f, 0.f, 0.f};

  for (int k0 = 0; k0 < 128; k0 += 32){
    bf16x8 ah[2], al[2];
    #pragma unroll
    for (int rt = 0; rt < 2; ++rt){
      int r = r0 + rt*16 + m16;
      if (r > n-1) r = n-1;
      const AT* ap = A + (size_t)r*128 + k0 + q*8;
      float fv[8];
      if constexpr (std::is_same<AT, float>::value){
        float4 f0 = *(const float4*)(ap);
        float4 f1 = *(const float4*)(ap + 4);
        fv[0]=f0.x; fv[1]=f0.y; fv[2]=f0.z; fv[3]=f0.w;
        fv[4]=f1.x; fv[5]=f1.y; fv[6]=f1.z; fv[7]=f1.w;
      } else {
        uint4 u = *(const uint4*)(ap);
        const __half2* hp = (const __half2*)&u;
        #pragma unroll
        for (int i = 0; i < 4; ++i){
          float2 f = __half22float2(hp[i]);
          fv[2*i] = f.x; fv[2*i+1] = f.y;
        }
      }
      #pragma unroll
      for (int j = 0; j < 8; ++j){
        unsigned p = split_tr(fv[j]);
        ah[rt][j] = (short)(p & 0xffff);
        al[rt][j] = (short)(p >> 16);
      }
    }
    #pragma unroll
    for (int ct = 0; ct < NCT; ++ct){
      int c = ct*16 + m16;
      const unsigned short* ph = Wh + (size_t)c*128 + k0 + q*8;
      const unsigned short* pl = Wl + (size_t)c*128 + k0 + q*8;
      bf16x8 bh = *(const bf16x8*)ph;
      bf16x8 bl = *(const bf16x8*)pl;
      #pragma unroll
      for (int rt = 0; rt < 2; ++rt){
        acc[rt][ct] = __builtin_amdgcn_mfma_f32_16x16x32_bf16(ah[rt], bh, acc[rt][ct], 0, 0, 0);
        acc[rt][ct] = __builtin_amdgcn_mfma_f32_16x16x32_bf16(ah[rt], bl, acc[rt][ct], 0, 0, 0);
        acc[rt][ct] = __builtin_amdgcn_mfma_f32_16x16x32_bf16(al[rt], bh, acc[rt][ct], 0, 0, 0);
      }
    }
  }
  // acc -> LDS tile
  #pragma unroll
  for (int rt = 0; rt < 2; ++rt){
    #pragma unroll
    for (int ct = 0; ct < NCT; ++ct){
      int c = ct*16 + m16;
      if (c < NC){
        float bv = BIAS ? bias[c] : 0.f;
        #pragma unroll
        for (int i = 0; i < 4; ++i)
          Cs[wave*32 + rt*16 + q*4 + i][c] = (CT)(acc[rt][ct][i] + bv);
      }
    }
  }
  __syncthreads();
  // coalesced writeout: 16B units
  constexpr int EPC = 16 / sizeof(CT);             // elems per 16B chunk
  constexpr int UPR = NC / EPC;                    // chunks per row
  for (int u = threadIdx.x; u < 128 * UPR; u += TPB){
    int row = u / UPR, ch = u - row * UPR;
    int r = rb + row;
    if (r < n)
      *(uint4*)(C + (size_t)r*NC + ch*EPC) = *(const uint4*)&Cs[row][ch*EPC];
  }
}

// ---------------- Aggregation: 16 lanes per dst node, 8 fp16 feats (16 B)/lane ----------------
// At the fabric wall (R9: 210MB fetch = 8 XCDs x 25.6MB buffer, ~3.5 TB/s) — unchanged.

template<int MODE>
__global__ __launch_bounds__(TPB) void agg_h(const __half* __restrict__ xh, const __half* __restrict__ resh,
                                             const float* __restrict__ dinv, const int* __restrict__ row_beg,
                                             const int* __restrict__ row_end, const int* __restrict__ csr_src,
                                             const float* __restrict__ bias, __half* __restrict__ outp, int n){
  int g = (int)((blockIdx.x * (unsigned)TPB + threadIdx.x) >> 4);
  if (g >= n) return;
  int lane = threadIdx.x & 15;
  float di = dinv[g];
  int beg = row_beg[g], end = row_end[g];

  float accA[8], accB[8];
  #pragma unroll
  for (int i = 0; i < 8; ++i){ accA[i] = 0.f; accB[i] = 0.f; }

  for (int base = beg; base < end; base += 16){
    int m = end - base; if (m > 16) m = 16;
    int   sl = (lane < m) ? csr_src[base + lane] : 0;
    float cl = (lane < m) ? dinv[sl] * di : 0.f;
    int mm = (m + 1) & ~1;
    for (int j = 0; j < mm; j += 2){
      int   s0 = __shfl(sl, j,   16), s1 = __shfl(sl, j+1, 16);
      float c0 = __shfl(cl, j,   16), c1 = __shfl(cl, j+1, 16);
      uint4 u0 = *(const uint4*)(xh + (size_t)s0 * 128 + lane * 8);
      uint4 u1 = *(const uint4*)(xh + (size_t)s1 * 128 + lane * 8);
      const __half2* h0 = (const __half2*)&u0;
      const __half2* h1 = (const __half2*)&u1;
      #pragma unroll
      for (int i = 0; i < 4; ++i){
        float2 f0 = __half22float2(h0[i]);
        float2 f1 = __half22float2(h1[i]);
        accA[2*i]   = fmaf(c0, f0.x, accA[2*i]);
        accA[2*i+1] = fmaf(c0, f0.y, accA[2*i+1]);
        accB[2*i]   = fmaf(c1, f1.x, accB[2*i]);
        accB[2*i+1] = fmaf(c1, f1.y, accB[2*i+1]);
      }
    }
  }
  {
    float sc = 2.0f * di * di;
    uint4 u = *(const uint4*)(xh + (size_t)g * 128 + lane * 8);
    const __half2* h = (const __half2*)&u;
    #pragma unroll
    for (int i = 0; i < 4; ++i){
      float2 f = __half22float2(h[i]);
      accA[2*i]   = fmaf(sc, f.x, accA[2*i]);
      accA[2*i+1] = fmaf(sc, f.y, accA[2*i+1]);
    }
  }
  #pragma unroll
  for (int i = 0; i < 8; ++i) accA[i] += accB[i];

  if (MODE != 2){
    float4 b0 = *(const float4*)(bias + lane*8);
    float4 b1 = *(const float4*)(bias + lane*8 + 4);
    accA[0]+=b0.x; accA[1]+=b0.y; accA[2]+=b0.z; accA[3]+=b0.w;
    accA[4]+=b1.x; accA[5]+=b1.y; accA[6]+=b1.z; accA[7]+=b1.w;
  }
  if (MODE == 1){
    uint4 ur = *(const uint4*)(resh + (size_t)g*128 + lane*8);
    const __half2* hr = (const __half2*)&ur;
    #pragma unroll
    for (int i = 0; i < 4; ++i){
      float2 f = __half22float2(hr[i]);
      accA[2*i]   += f.x;
      accA[2*i+1] += f.y;
    }
  }
  if (MODE != 2){
    #pragma unroll
    for (int i = 0; i < 8; ++i) accA[i] = gelu_erf(accA[i]);
  }
  __half hv[8];
  #pragma unroll
  for (int i = 0; i < 8; ++i) hv[i] = __float2half(accA[i]);
  *(uint4*)(outp + (size_t)g*128 + lane*8) = *(const uint4*)hv;
}

// ---------------- launch ----------------

extern "C" void kernel_launch(void* const* d_in, const int* in_sizes, int n_in,
                              void* d_out, int out_size, void* d_ws, size_t ws_size,
                              hipStream_t stream){
  const float* x  = (const float*)d_in[0];
  const int*   ei = (const int*)d_in[1];
  const float* W0 = (const float*)d_in[2];
  const float* b0 = (const float*)d_in[3];
  const float* W1 = (const float*)d_in[4];
  const float* b1 = (const float*)d_in[5];
  const float* W2 = (const float*)d_in[6];
  const float* b2 = (const float*)d_in[7];
  const float* W3 = (const float*)d_in[8];
  const float* b3 = (const float*)d_in[9];
  float* out = (float*)d_out;

  const int N = in_sizes[0] / 128;
  const int E = in_sizes[1] / 2;
  const int* src = ei;
  const int* dst = ei + E;
  const int nper = (N + BKT - 1) / BKT;   // 391
  const unsigned long long inv = ((1ULL << 40) + nper - 1) / (unsigned long long)nper;

  char* ws = (char*)d_ws;
  size_t off = 0;
  auto alloc = [&](size_t bytes) -> void* {
    void* p = ws + off;
    off += (bytes + 255) & ~(size_t)255;
    return p;
  };
  __half* xw_h  = (__half*)alloc((size_t)N * 128 * 2);
  __half* g0    = (__half*)alloc((size_t)N * 128 * 2);
  __half* g1    = (__half*)alloc((size_t)N * 128 * 2);
  __half* g2    = (__half*)alloc((size_t)N * 128 * 2);
  int* csr      = (int*)   alloc((size_t)BKT * BCAP * 4);
  int* bucketed = (int*)   alloc((size_t)BKT * BCAP * 4);
  int* row_beg  = (int*)   alloc((size_t)N * 4);
  int* row_end  = (int*)   alloc((size_t)N * 4);
  float* dnv    = (float*) alloc((size_t)N * 4);
  int* bcnt     = (int*)   alloc((size_t)BKT * 4);
  const int WTOT = 3*16384 + 48*128;
  unsigned short* Wh = (unsigned short*)alloc((size_t)WTOT * 2);
  unsigned short* Wl = (unsigned short*)alloc((size_t)WTOT * 2);
  (void)ws_size; (void)n_in; (void)out_size;

  (void)hipMemsetAsync(bcnt, 0, (size_t)BKT * 4, stream);
  const int WB = (WTOT + TPB - 1) / TPB;
  prep_kernel<<<CHK + WB, TPB, 0, stream>>>(src, dst, bcnt, bucketed, W0, W1, W2, W3, Wh, Wl, E, nper, inv);
  bucket_csr<<<BKT, TPB, 0, stream>>>(bucketed, bcnt, csr, row_beg, row_end, dnv, N, nper);

  int gblocks = (N + 127) / 128;
  int ablocks = ((size_t)N * 16 + TPB - 1) / TPB;

  const unsigned short* W0h = Wh,          *W0l = Wl;
  const unsigned short* W1h = Wh + 16384,  *W1l = Wl + 16384;
  const unsigned short* W2h = Wh + 32768,  *W2l = Wl + 32768;
  const unsigned short* W3h = Wh + 49152,  *W3l = Wl + 49152;

  // L0: g0 = gelu(conv(x))
  gemm_mfma<8,128,false,float,__half><<<gblocks, TPB, 0, stream>>>(x, W0h, W0l, nullptr, xw_h, N);
  agg_h<0><<<ablocks, TPB, 0, stream>>>(xw_h, nullptr, dnv, row_beg, row_end, csr, b0, g0, N);
  // L1: g1 = gelu(g0 + conv(g0))
  gemm_mfma<8,128,false,__half,__half><<<gblocks, TPB, 0, stream>>>(g0, W1h, W1l, nullptr, xw_h, N);
  agg_h<1><<<ablocks, TPB, 0, stream>>>(xw_h, g0, dnv, row_beg, row_end, csr, b1, g1, N);
  // L2: g2 = gelu(g1 + conv(g1))
  gemm_mfma<8,128,false,__half,__half><<<gblocks, TPB, 0, stream>>>(g1, W2h, W2l, nullptr, xw_h, N);
  agg_h<1><<<ablocks, TPB, 0, stream>>>(xw_h, g1, dnv, row_beg, row_end, csr, b2, g2, N);
  // L3: out = Agg(g2) @ W3 + b3   (Agg commutes with right-multiplication)
  agg_h<2><<<ablocks, TPB, 0, stream>>>(g2, nullptr, dnv, row_beg, row_end, csr, nullptr, xw_h, N);
  gemm_mfma<3,40,true,__half,float><<<gblocks, TPB, 0, stream>>>(xw_h, W3h, W3l, b3, out, N);
}